// Round 1
// baseline (1160.988 us; speedup 1.0000x reference)
//
#include <hip/hip_runtime.h>
#include <stdint.h>

typedef unsigned short u16;
typedef __bf16 bf16t;
typedef bf16t bf16x8 __attribute__((ext_vector_type(8)));
typedef float f32x4 __attribute__((ext_vector_type(4)));

#define NROWS 100000
#define DD 512
#define QD 128
#define KSEL 20000

// ---------- helpers ----------
__device__ __forceinline__ uint32_t fmono(float x){
  uint32_t u = __float_as_uint(x);
  return (u & 0x80000000u) ? ~u : (u | 0x80000000u);
}
__device__ __forceinline__ float fdemono(uint32_t k){
  uint32_t u = (k & 0x80000000u) ? (k & 0x7fffffffu) : ~k;
  return __uint_as_float(u);
}
__device__ __forceinline__ u16 f2bf(float x){  // RNE float->bf16 bits
  uint32_t u = __float_as_uint(x);
  u += 0x7fffu + ((u >> 16) & 1u);
  return (u16)(u >> 16);
}

struct Scal {
  uint32_t sel_hi, cnt_before, keyT, gmk;
  float Z;
  uint32_t pad0, pad1, pad2;
  unsigned long long ck[2];   // argmax keys for c columns
};

// ---------- small kernels ----------
__global__ void k_conv(const float* __restrict__ Wl, const float* __restrict__ Wv,
                       const float* __restrict__ Wq, u16* __restrict__ wl_bf, u16* __restrict__ wvq_bf){
  int idx = blockIdx.x*256 + threadIdx.x;          // 589824 total
  if (idx < 262144) wl_bf[idx] = f2bf(Wl[idx]);
  int e = idx - 262144;
  if (e >= 0) wvq_bf[e] = f2bf(e < 262144 ? Wv[e] : Wq[e - 262144]);
}

__global__ void k_hist1(const float* __restrict__ preds, uint32_t* __restrict__ hist){
  int idx = blockIdx.x*256 + threadIdx.x;
  if (idx < NROWS) atomicAdd(&hist[fmono(preds[idx]) >> 16], 1u);
}

__global__ void k_sel1(const uint32_t* __restrict__ hist, Scal* sc){
  __shared__ uint32_t part[256];
  int t = threadIdx.x;
  uint32_t s = 0;
  for (int b = 0; b < 256; ++b) s += hist[t*256 + b];
  part[t] = s; __syncthreads();
  if (t == 0){
    uint32_t cum = 0;
    for (int p = 0; p < 256; ++p){
      if (cum + part[p] >= KSEL){
        uint32_t c2 = cum;
        for (int b = p*256; b < p*256 + 256; ++b){
          uint32_t hb = hist[b];
          if (c2 + hb >= KSEL){ sc->sel_hi = (uint32_t)b; sc->cnt_before = c2; break; }
          c2 += hb;
        }
        break;
      }
      cum += part[p];
    }
  }
}

__global__ void k_hist2(const float* __restrict__ preds, const Scal* sc, uint32_t* __restrict__ hist){
  int idx = blockIdx.x*256 + threadIdx.x;
  uint32_t sh = sc->sel_hi;
  if (idx < NROWS){
    uint32_t key = fmono(preds[idx]);
    if ((key >> 16) == sh) atomicAdd(&hist[key & 0xffffu], 1u);
  }
}

__global__ void k_sel2(const uint32_t* __restrict__ hist, Scal* sc){
  __shared__ uint32_t part[256];
  int t = threadIdx.x;
  uint32_t s = 0;
  for (int b = 0; b < 256; ++b) s += hist[t*256 + b];
  part[t] = s; __syncthreads();
  if (t == 0){
    uint32_t target = KSEL - sc->cnt_before;
    uint32_t cum = 0;
    for (int p = 0; p < 256; ++p){
      if (cum + part[p] >= target){
        uint32_t c2 = cum;
        for (int b = p*256; b < p*256 + 256; ++b){
          uint32_t hb = hist[b];
          if (c2 + hb >= target){ sc->keyT = (sc->sel_hi << 16) | (uint32_t)b; break; }
          c2 += hb;
        }
        break;
      }
      cum += part[p];
    }
  }
}

__global__ void k_gmax(const float* __restrict__ preds, Scal* sc){
  int idx = blockIdx.x*256 + threadIdx.x;
  uint32_t kT = sc->keyT;
  uint32_t km = 0;
  if (idx < NROWS){
    float p = preds[idx];
    float pm = (fmono(p) <= kT) ? 0.0f : p;
    km = fmono(pm);
  }
  #pragma unroll
  for (int off = 32; off; off >>= 1){ uint32_t o = __shfl_xor(km, off); km = km > o ? km : o; }
  if ((threadIdx.x & 63) == 0) atomicMax(&sc->gmk, km);
}

__global__ void k_sumexp(const float* __restrict__ preds, Scal* sc){
  int idx = blockIdx.x*256 + threadIdx.x;
  uint32_t kT = sc->keyT;
  float gm = fdemono(sc->gmk);
  float s = 0.f;
  if (idx < NROWS){
    float p = preds[idx];
    float pm = (fmono(p) <= kT) ? 0.0f : p;
    s = expf(pm - gm);
  }
  #pragma unroll
  for (int off = 32; off; off >>= 1) s += __shfl_xor(s, off);
  if ((threadIdx.x & 63) == 0) atomicAdd(&sc->Z, s);
}

__global__ void k_argc(const float* __restrict__ c, Scal* sc){
  int idx = blockIdx.x*256 + threadIdx.x;
  unsigned long long k0 = 0, k1 = 0;
  if (idx < NROWS){
    uint32_t inv = ~(uint32_t)idx;
    k0 = ((unsigned long long)fmono(c[(size_t)idx*2 + 0]) << 32) | inv;
    k1 = ((unsigned long long)fmono(c[(size_t)idx*2 + 1]) << 32) | inv;
  }
  #pragma unroll
  for (int off = 32; off; off >>= 1){
    unsigned long long o0 = __shfl_xor(k0, off); if (o0 > k0) k0 = o0;
    unsigned long long o1 = __shfl_xor(k1, off); if (o1 > k1) k1 = o1;
  }
  if ((threadIdx.x & 63) == 0){ atomicMax(&sc->ck[0], k0); atomicMax(&sc->ck[1], k1); }
}

// exact fp32 f rows at the two argmax indices
__global__ void k_mfeat(const float* __restrict__ feats, const float* __restrict__ preds,
                        const float* __restrict__ Wl, const float* __restrict__ bl,
                        const Scal* sc, float* __restrict__ fm){
  int j = blockIdx.x;
  int t = threadIdx.x;
  uint32_t m = ~(uint32_t)(sc->ck[j] & 0xffffffffull);
  float p = preds[m];
  float pm = (fmono(p) <= sc->keyT) ? 0.f : p;
  float g = 1.f + expf(pm - fdemono(sc->gmk)) / sc->Z;
  const float* fr = feats + (size_t)m * DD;
  for (int n = t; n < DD; n += 256){
    const float* wr = Wl + (size_t)n * DD;
    float acc = 0.f;
    for (int k = 0; k < DD; ++k) acc += fr[k] * wr[k];
    float v = bl[n] + g * acc;
    fm[j*DD + n] = v > 0.f ? v : 0.f;
  }
}

__global__ void k_qmax(const float* __restrict__ fm, const float* __restrict__ Wq,
                       const float* __restrict__ bq, float* __restrict__ qmv){
  int t = threadIdx.x;
  int j = t >> 7, q = t & 127;
  const float* fr = fm + j*DD;
  const float* wr = Wq + (size_t)q * DD;
  float acc = 0.f;
  for (int k = 0; k < DD; ++k) acc += fr[k] * wr[k];
  qmv[j*QD + q] = tanhf(bq[q] + acc);
}

// ---------- the fused heavy kernel ----------
#define MFMA16(A,B,C) __builtin_amdgcn_mfma_f32_16x16x32_bf16(A,B,C,0,0,0)

__launch_bounds__(256, 2)
__global__ void k_main(const float* __restrict__ feats, const float* __restrict__ preds,
                       const u16* __restrict__ wl_bf, const u16* __restrict__ wvq_bf,
                       const float* __restrict__ bl, const float* __restrict__ bv,
                       const float* __restrict__ bq, const float* __restrict__ qmv,
                       const Scal* __restrict__ sc,
                       float* __restrict__ sumE, float* __restrict__ sumEV,
                       float* __restrict__ Aout){
  // LDS unions (bytes):
  // stage1: W1 [512][40] u16 @0 (40960), AT [32][40] u16 @40960 (2560)
  // stage2: F  [32][520] u16 @0 (33280), W2 [320][40] u16 @33280 (25600)
  // epilogue: Qlds [32][128] f32 @0 (16384), Elds [32][2] f32 @16384
  __shared__ __align__(16) char smem[58880];
  u16* W1 = (u16*)smem;
  u16* AT = (u16*)(smem + 40960);
  u16* F  = (u16*)smem;
  u16* W2 = (u16*)(smem + 33280);
  float* Qlds = (float*)smem;
  float* Elds = (float*)(smem + 16384);

  const int tid = threadIdx.x;
  const int wave = tid >> 6, lane = tid & 63, quad = lane >> 4, l16 = lane & 15;
  const int i0 = blockIdx.x * 32;

  // staging row and its softmax scale g
  const int rA = tid >> 3;
  const int kposA = (tid & 7) * 4;
  const int iA = i0 + rA;
  float gA;
  {
    float p = preds[iA];
    float pm = (fmono(p) <= sc->keyT) ? 0.f : p;
    gA = 1.f + expf(pm - fdemono(sc->gmk)) / sc->Z;
  }

  f32x4 acc1[2][8];
  #pragma unroll
  for (int a = 0; a < 2; ++a)
    #pragma unroll
    for (int b = 0; b < 8; ++b)
      #pragma unroll
      for (int r = 0; r < 4; ++r) acc1[a][b][r] = 0.f;

  // -------- stage 1: f = relu(gX @ Wlin^T + b) --------
  for (int kc = 0; kc < 16; ++kc){
    __syncthreads();
    { // stage A tile (32 x 32 fp32 -> bf16*g)
      float4 v = *(const float4*)(feats + (size_t)iA*DD + kc*32 + kposA);
      uint2 pk;
      pk.x = (uint32_t)f2bf(v.x*gA) | ((uint32_t)f2bf(v.y*gA) << 16);
      pk.y = (uint32_t)f2bf(v.z*gA) | ((uint32_t)f2bf(v.w*gA) << 16);
      *(uint2*)(AT + rA*40 + kposA) = pk;
    }
    { // stage W1 tile (512 x 32 bf16)
      const uint4* s0 = (const uint4*)(wl_bf + (size_t)tid*DD + kc*32);
      uint4* d0 = (uint4*)(W1 + tid*40);
      d0[0]=s0[0]; d0[1]=s0[1]; d0[2]=s0[2]; d0[3]=s0[3];
      const uint4* s1 = (const uint4*)(wl_bf + (size_t)(tid+256)*DD + kc*32);
      uint4* d1 = (uint4*)(W1 + (tid+256)*40);
      d1[0]=s1[0]; d1[1]=s1[1]; d1[2]=s1[2]; d1[3]=s1[3];
    }
    __syncthreads();
    bf16x8 a0 = *(const bf16x8*)(AT + l16*40 + quad*8);
    bf16x8 a1 = *(const bf16x8*)(AT + (16 + l16)*40 + quad*8);
    #pragma unroll
    for (int ct = 0; ct < 8; ++ct){
      bf16x8 bfr = *(const bf16x8*)(W1 + (wave*128 + ct*16 + l16)*40 + quad*8);
      acc1[0][ct] = MFMA16(a0, bfr, acc1[0][ct]);
      acc1[1][ct] = MFMA16(a1, bfr, acc1[1][ct]);
    }
  }
  __syncthreads();
  // write f (bias + relu) to LDS as bf16
  #pragma unroll
  for (int ct = 0; ct < 8; ++ct){
    int col = wave*128 + ct*16 + l16;
    float blv = bl[col];
    #pragma unroll
    for (int rt = 0; rt < 2; ++rt)
      #pragma unroll
      for (int r = 0; r < 4; ++r){
        int row = rt*16 + quad*4 + r;
        float v = acc1[rt][ct][r] + blv;
        v = v > 0.f ? v : 0.f;
        F[row*520 + col] = f2bf(v);
      }
  }

  // -------- stage 2: [V | Q] = f @ [Wv;Wq]^T --------
  f32x4 acc2[2][10];
  #pragma unroll
  for (int a = 0; a < 2; ++a)
    #pragma unroll
    for (int b = 0; b < 10; ++b)
      #pragma unroll
      for (int r = 0; r < 4; ++r) acc2[a][b][r] = 0.f;

  for (int h = 0; h < 2; ++h){
    for (int kc = 0; kc < 16; ++kc){
      __syncthreads();
      for (int r = tid; r < 320; r += 256){
        const uint4* s = (const uint4*)(wvq_bf + (size_t)(h*320 + r)*DD + kc*32);
        uint4* d = (uint4*)(W2 + r*40);
        d[0]=s[0]; d[1]=s[1]; d[2]=s[2]; d[3]=s[3];
      }
      __syncthreads();
      bf16x8 a0 = *(const bf16x8*)(F + l16*520 + kc*32 + quad*8);
      bf16x8 a1 = *(const bf16x8*)(F + (16 + l16)*520 + kc*32 + quad*8);
      #pragma unroll
      for (int ct = 0; ct < 5; ++ct){
        bf16x8 bfr = *(const bf16x8*)(W2 + (wave*80 + ct*16 + l16)*40 + quad*8);
        acc2[0][h*5 + ct] = MFMA16(a0, bfr, acc2[0][h*5 + ct]);
        acc2[1][h*5 + ct] = MFMA16(a1, bfr, acc2[1][h*5 + ct]);
      }
    }
  }
  __syncthreads();   // done reading F/W2; reuse smem for Qlds/Elds

  // epilogue part 1: biases; Q tiles -> tanh -> Qlds
  #pragma unroll
  for (int t2 = 0; t2 < 10; ++t2){
    int hh = t2 / 5, ct = t2 % 5;
    int col = hh*320 + wave*80 + ct*16 + l16;
    if (col >= 512){
      int qc = col - 512;
      float bqv = bq[qc];
      #pragma unroll
      for (int rt = 0; rt < 2; ++rt)
        #pragma unroll
        for (int r = 0; r < 4; ++r){
          int row = rt*16 + quad*4 + r;
          Qlds[row*QD + qc] = tanhf(acc2[rt][t2][r] + bqv);
        }
    } else {
      float bvv = bv[col];
      #pragma unroll
      for (int rt = 0; rt < 2; ++rt)
        #pragma unroll
        for (int r = 0; r < 4; ++r) acc2[rt][t2][r] += bvv;
    }
  }
  __syncthreads();

  // epilogue part 2: scores + exp (unnormalized A)
  {
    int dd = tid >> 2, sub = tid & 3;
    int row = dd >> 1, j = dd & 1;
    const float* q = qmv + j*QD;
    const float* Ql = Qlds + row*QD;
    float part = 0.f;
    int kk0 = sub * 32;
    #pragma unroll 8
    for (int k = 0; k < 32; ++k) part += Ql[kk0 + k] * q[kk0 + k];
    part += __shfl_xor(part, 1);
    part += __shfl_xor(part, 2);
    if (sub == 0){
      float e = expf(part * 0.08838834764831845f);  // 1/sqrt(128)
      Elds[row*2 + j] = e;
      Aout[(size_t)(i0 + row)*2 + j] = e;
    }
  }
  __syncthreads();

  if (tid < 2){
    float s = 0.f;
    for (int r = 0; r < 32; ++r) s += Elds[r*2 + tid];
    atomicAdd(&sumE[tid], s);
  }

  // epilogue part 3: B partials = sum_i e[i][j] * V[i][col]
  #pragma unroll
  for (int t2 = 0; t2 < 10; ++t2){
    int hh = t2 / 5, ct = t2 % 5;
    int col = hh*320 + wave*80 + ct*16 + l16;
    if (col < 512){
      float b0 = 0.f, b1 = 0.f;
      #pragma unroll
      for (int rt = 0; rt < 2; ++rt)
        #pragma unroll
        for (int r = 0; r < 4; ++r){
          int row = rt*16 + quad*4 + r;
          float v = acc2[rt][t2][r];
          b0 += v * Elds[row*2 + 0];
          b1 += v * Elds[row*2 + 1];
        }
      b0 += __shfl_xor(b0, 16); b0 += __shfl_xor(b0, 32);
      b1 += __shfl_xor(b1, 16); b1 += __shfl_xor(b1, 32);
      if (quad == 0){
        atomicAdd(&sumEV[col], b0);
        atomicAdd(&sumEV[512 + col], b1);
      }
    }
  }
}

__global__ void k_norm(float* __restrict__ Aout, const float* __restrict__ sumE){
  int idx = blockIdx.x*256 + threadIdx.x;
  if (idx < 200000) Aout[idx] = Aout[idx] / sumE[idx & 1];
}

__global__ void k_final(const float* __restrict__ sumEV, const float* __restrict__ sumE,
                        const float* __restrict__ Wfcc, const float* __restrict__ bfcc,
                        float* __restrict__ out){
  __shared__ float red[512];
  int t = threadIdx.x;
  float z0 = sumE[0], z1 = sumE[1];
  float c0 = 0.f, c1 = 0.f;
  for (int e = t; e < 1024; e += 256){
    float bvv = sumEV[e] / ((e >> 9) ? z1 : z0);
    out[200002 + e] = bvv;
    c0 += bvv * Wfcc[e];
    c1 += bvv * Wfcc[1024 + e];
  }
  red[t] = c0; red[256 + t] = c1;
  __syncthreads();
  for (int s = 128; s; s >>= 1){
    if (t < s){ red[t] += red[t + s]; red[256 + t] += red[256 + t + s]; }
    __syncthreads();
  }
  if (t == 0){ out[0] = red[0] + bfcc[0]; out[1] = red[256] + bfcc[1]; }
}

// ---------- launch ----------
extern "C" void kernel_launch(void* const* d_in, const int* in_sizes, int n_in,
                              void* d_out, int out_size, void* d_ws, size_t ws_size,
                              hipStream_t stream){
  (void)in_sizes; (void)n_in; (void)out_size; (void)ws_size;
  const float* feats = (const float*)d_in[0];
  const float* c     = (const float*)d_in[1];
  const float* preds = (const float*)d_in[2];
  const float* W_lin = (const float*)d_in[3];
  const float* b_lin = (const float*)d_in[4];
  const float* W_q   = (const float*)d_in[5];
  const float* b_q   = (const float*)d_in[6];
  const float* W_v   = (const float*)d_in[7];
  const float* b_v   = (const float*)d_in[8];
  const float* W_fcc = (const float*)d_in[9];
  const float* b_fcc = (const float*)d_in[10];
  float* out = (float*)d_out;
  char* ws = (char*)d_ws;

  // ws layout (bytes)
  u16*      wl_bf  = (u16*)(ws + 0);            // 524288
  u16*      wvq_bf = (u16*)(ws + 524288);       // 655360  -> 1179648
  uint32_t* hist1  = (uint32_t*)(ws + 1179648); // 262144  -> 1441792
  uint32_t* hist2  = (uint32_t*)(ws + 1441792); // 262144  -> 1703936
  Scal*     sc     = (Scal*)(ws + 1703936);     // 48      (pad to 64)
  float*    fm     = (float*)(ws + 1704000);    // 4096    -> 1708096
  float*    qmv    = (float*)(ws + 1708096);    // 1024    -> 1709120
  float*    sumE   = (float*)(ws + 1709120);    // 8
  float*    sumEV  = (float*)(ws + 1709136);    // 4096    -> 1713232

  hipMemsetAsync(ws + 1179648, 0, 1713232 - 1179648, stream);

  k_conv  <<<2304, 256, 0, stream>>>(W_lin, W_v, W_q, wl_bf, wvq_bf);
  k_hist1 <<<391, 256, 0, stream>>>(preds, hist1);
  k_sel1  <<<1, 256, 0, stream>>>(hist1, sc);
  k_hist2 <<<391, 256, 0, stream>>>(preds, sc, hist2);
  k_sel2  <<<1, 256, 0, stream>>>(hist2, sc);
  k_gmax  <<<391, 256, 0, stream>>>(preds, sc);
  k_sumexp<<<391, 256, 0, stream>>>(preds, sc);
  k_argc  <<<391, 256, 0, stream>>>(c, sc);
  k_mfeat <<<2, 256, 0, stream>>>(feats, preds, W_lin, b_lin, sc, fm);
  k_qmax  <<<1, 256, 0, stream>>>(fm, W_q, b_q, qmv);
  k_main  <<<3125, 256, 0, stream>>>(feats, preds, wl_bf, wvq_bf, b_lin, b_v, b_q,
                                     qmv, sc, sumE, sumEV, out + 2);
  k_norm  <<<782, 256, 0, stream>>>(out + 2, sumE);
  k_final <<<1, 256, 0, stream>>>(sumEV, sumE, W_fcc, b_fcc, out);
}